// Round 3
// baseline (1681.709 us; speedup 1.0000x reference)
//
#include <hip/hip_runtime.h>
#include <stdint.h>
#include <stddef.h>

#define NN 25000     // nodes
#define NPAD 25008   // 1563*16
#define NBLK 1563    // node blocks of 16
#define NE 100000    // edges
#define FEAT 16
#define DD 64
#define NGG 512
#define NJ 1024
#define NS 2048
#define NO 105
#define SLOPE 0.01f
#define CTOT 4160    // 4096 A-columns + 64 bias columns
#define ASTRIDE 8352 // bytes per node row in LDS: 4160*2 + 32 pad (16B aligned)

typedef short bf8 __attribute__((ext_vector_type(8)));   // 8 bf16 raw bits (4 VGPR)
typedef float f32x4 __attribute__((ext_vector_type(4)));

__device__ __forceinline__ float lk(float v){ return v > 0.f ? v : SLOPE*v; }
__device__ __forceinline__ unsigned short f2bf(float f){
  unsigned int x = __float_as_uint(f);
  x += 0x7fffu + ((x>>16)&1u);           // round-to-nearest-even
  return (unsigned short)(x>>16);
}
__device__ __forceinline__ float bf2f(unsigned short u){ return __uint_as_float(((unsigned int)u)<<16); }
__device__ __forceinline__ float sg(float x){ return 1.f/(1.f+expf(-x)); }
__device__ __forceinline__ unsigned fenc(float f){ unsigned u = __float_as_uint(f); return (u & 0x80000000u) ? ~u : (u | 0x80000000u); }
__device__ __forceinline__ float fdec(unsigned k){ unsigned u = (k & 0x80000000u) ? (k ^ 0x80000000u) : ~k; return __uint_as_float(u); }

// ---------- setup kernels ----------

// out = leaky(x @ lin0_w.T + lin0_b); also writes bf16 copy
__global__ __launch_bounds__(256) void k_lin0(const float* __restrict__ x, const float* __restrict__ w,
                       const float* __restrict__ b, float* __restrict__ h, unsigned short* __restrict__ hbf){
  int wid = (blockIdx.x*blockDim.x + threadIdx.x) >> 6;
  int lane = threadIdx.x & 63;
  if (wid >= NN) return;
  float xv = lane < FEAT ? x[wid*FEAT + lane] : 0.f;
  float acc = b[lane];
  #pragma unroll
  for (int f=0; f<FEAT; ++f) acc += __shfl(xv, f) * w[lane*FEAT + f];
  float v = lk(acc);
  h[wid*DD + lane] = v;
  hbf[wid*DD + lane] = f2bf(v);
}

// w2x[c*64+i]: c<4096 -> bf16(net2_w[i*4096+c]) ; c=4096+o -> bf16(net2_b[i*64+o])
__global__ __launch_bounds__(256) void k_w2x(const float* __restrict__ w2, const float* __restrict__ b2,
                                             unsigned short* __restrict__ o){
  int t = blockIdx.x*blockDim.x + threadIdx.x;
  if (t >= CTOT*DD) return;
  int c = t >> 6, i = t & 63;
  float v = (c < 4096) ? w2[(size_t)i*4096 + c] : b2[i*64 + (c - 4096)];
  o[t] = f2bf(v);
}

// generic transpose: T[c*R + r] = M[r*C + c]
__global__ __launch_bounds__(256) void k_tr(const float* __restrict__ m, float* __restrict__ t, int R, int C){
  int i = blockIdx.x*blockDim.x + threadIdx.x;
  if (i >= R*C) return;
  int r = i / C, c = i - r*C;
  t[c*R + r] = m[i];
}

__global__ __launch_bounds__(256) void k_deg(const int* __restrict__ dst, float* __restrict__ deg){
  int e = blockIdx.x*blockDim.x + threadIdx.x;
  if (e < NE) atomicAdd(&deg[dst[e]], 1.f);
}
__global__ __launch_bounds__(256) void k_invd(float* __restrict__ d){
  int n = blockIdx.x*blockDim.x + threadIdx.x;
  if (n < NN) d[n] = d[n] > 0.f ? 1.f/d[n] : 0.f;
}

// ---------- edge sort by src (counting sort) ----------
__global__ __launch_bounds__(256) void k_hist(const int* __restrict__ src, int* __restrict__ degS){
  int e = blockIdx.x*blockDim.x + threadIdx.x;
  if (e < NE) atomicAdd(&degS[src[e]], 1);
}
// single-block inclusive scan -> rowptr[0..NPAD]
__global__ __launch_bounds__(1024) void k_scan(const int* __restrict__ degS, int* __restrict__ rowptr){
  __shared__ int buf[1024];
  __shared__ int base;
  int tid = threadIdx.x;
  if (tid == 0){ base = 0; rowptr[0] = 0; }
  __syncthreads();
  for (int c0 = 0; c0 < NPAD; c0 += 1024){
    int i = c0 + tid;
    int v = (i < NPAD) ? degS[i] : 0;
    buf[tid] = v; __syncthreads();
    for (int off=1; off<1024; off<<=1){
      int t = (tid >= off) ? buf[tid-off] : 0;
      __syncthreads();
      buf[tid] += t;
      __syncthreads();
    }
    if (i < NPAD) rowptr[i+1] = base + buf[tid];
    __syncthreads();
    if (tid == 0) base += buf[1023];
    __syncthreads();
  }
}
__global__ __launch_bounds__(256) void k_scatter(const int* __restrict__ src, const int* __restrict__ dst,
                         const int* __restrict__ rowptr, int* __restrict__ cnt,
                         int* __restrict__ sSrc, int* __restrict__ sDst, int* __restrict__ sEid){
  int e = blockIdx.x*blockDim.x + threadIdx.x;
  if (e >= NE) return;
  int s = src[e];
  int pos = rowptr[s] + atomicAdd(&cnt[s], 1);
  sSrc[pos] = s; sDst[pos] = dst[e]; sEid[pos] = e;
}
// e1 sorted: e1s[pos][k] = bf16(leaky(edge_attr[sEid[pos]] @ net1_w.T + net1_b))
__global__ __launch_bounds__(256) void k_e1s(const float* __restrict__ ea, const float* __restrict__ w,
                     const float* __restrict__ b, const int* __restrict__ sEid,
                     unsigned short* __restrict__ e1s){
  int t = blockIdx.x*blockDim.x + threadIdx.x;   // t = pos*64 + k
  if (t >= NE*DD) return;
  int pos = t >> 6, k = t & 63;
  int e = sEid[pos];
  float acc = b[k];
  #pragma unroll
  for (int a=0; a<4; ++a) acc += ea[e*4+a] * w[k*4+a];
  e1s[t] = f2bf(lk(acc));
}

// ---------- fused: per 16-node block, A-tile in LDS, then edge matvecs ----------
// Phase A: A[c][n] = sum_i w2x[c][i] * hbf[n][i]  (MFMA: A-op rows = c, B-op cols = n)
//   C/D: col=lane&15 (=n), row=(lane>>4)*4+j (=c within tile)  [HW-verified]
// LDS layout: per node n: bf16 A[n][c], c in [0,4160), byte addr n*ASTRIDE + c*2.
// Phase B: per sorted edge of block's nodes: msg[o] = sum_k e1[k]*A[n][o*64+k] + A[n][4096+o]
__global__ __launch_bounds__(512) void k_fused8(const unsigned short* __restrict__ w2x,
                                                const unsigned short* __restrict__ hbf,
                                                const unsigned short* __restrict__ e1s,
                                                const int* __restrict__ sSrc, const int* __restrict__ sDst,
                                                const int* __restrict__ rowptr,
                                                float* __restrict__ aggr){
  extern __shared__ char smem[];
  int lane = threadIdx.x & 63;
  int wv   = threadIdx.x >> 6;           // 0..7
  int n0   = blockIdx.x * 16;
  int r16 = lane & 15, kg = lane >> 4;

  // persistent B-fragments: bf16 h rows of the 16 nodes
  const unsigned short* hp = hbf + (size_t)(n0 + r16)*DD;
  bf8 bh0 = *(const bf8*)(hp + kg*8);
  bf8 bh1 = *(const bf8*)(hp + 32 + kg*8);

  // phase A: 260 c-tiles round-robin over 8 waves
  for (int t = wv; t < 260; t += 8){
    const unsigned short* wp = w2x + (size_t)t*1024 + r16*64;
    bf8 a0 = *(const bf8*)(wp + kg*8);
    bf8 a1 = *(const bf8*)(wp + 32 + kg*8);
    f32x4 acc = {0.f,0.f,0.f,0.f};
    acc = __builtin_amdgcn_mfma_f32_16x16x32_bf16(a0, bh0, acc, 0,0,0);
    acc = __builtin_amdgcn_mfma_f32_16x16x32_bf16(a1, bh1, acc, 0,0,0);
    unsigned u0 = (unsigned)f2bf(acc[0]) | ((unsigned)f2bf(acc[1]) << 16);
    unsigned u1 = (unsigned)f2bf(acc[2]) | ((unsigned)f2bf(acc[3]) << 16);
    unsigned long long ull = (unsigned long long)u0 | ((unsigned long long)u1 << 32);
    *(unsigned long long*)(smem + (size_t)r16*ASTRIDE + t*32 + kg*8) = ull;
  }
  __syncthreads();

  // phase B: edges of these 16 nodes
  int estart = rowptr[n0], eend = rowptr[n0 + 16];
  int rg = lane >> 3, cg = lane & 7;
  for (int ei = estart + wv; ei < eend; ei += 8){
    int nl = sSrc[ei] - n0;
    int d  = sDst[ei];
    bf8 ef = *(const bf8*)(e1s + (size_t)ei*DD + cg*8);
    float e1f[8];
    #pragma unroll
    for (int j=0; j<8; ++j) e1f[j] = bf2f((unsigned short)ef[j]);
    const char* ab = smem + (size_t)nl*ASTRIDE;
    float acc8[8];
    #pragma unroll
    for (int st=0; st<8; ++st){
      bf8 Av = *(const bf8*)(ab + (st*8 + rg)*128 + cg*16);
      float s = 0.f;
      #pragma unroll
      for (int j=0; j<8; ++j) s += bf2f((unsigned short)Av[j]) * e1f[j];
      acc8[st] = s;
    }
    #pragma unroll
    for (int off=1; off<8; off<<=1)
      #pragma unroll
      for (int st=0; st<8; ++st) acc8[st] += __shfl_xor(acc8[st], off);
    int o = cg*8 + rg;
    float v = acc8[0];
    #pragma unroll
    for (int j=1; j<8; ++j) v = (cg == j) ? acc8[j] : v;
    v += bf2f(*(const unsigned short*)(ab + 8192 + o*2));
    atomicAdd(&aggr[(size_t)d*DD + o], v);
  }
}

// ---------- fused NNConv-root + GRU (also emits bf16 h) ----------
#define NB 8
__global__ __launch_bounds__(256) void k_gru(float* __restrict__ h, unsigned short* __restrict__ hbf,
                      const float* __restrict__ aggr,
                      const float* __restrict__ invd,
                      const float* __restrict__ cr, const float* __restrict__ cb,
                      const float* __restrict__ wihT, const float* __restrict__ whhT,
                      const float* __restrict__ bih, const float* __restrict__ bhh){
  int wid = (blockIdx.x*blockDim.x + threadIdx.x) >> 6;
  int lane = threadIdx.x & 63;
  int nb0 = wid * NB;
  if (nb0 >= NN) return;
  int cnt = NN - nb0 < NB ? NN - nb0 : NB;

  float hreg[NB], mreg[NB], mac[NB];
  #pragma unroll
  for (int t=0; t<NB; ++t){ hreg[t] = (t<cnt) ? h[(size_t)(nb0+t)*DD + lane] : 0.f; mac[t]=0.f; }
  for (int i=0; i<DD; ++i){
    float crv = cr[i*DD + lane];
    #pragma unroll
    for (int t=0; t<NB; ++t) mac[t] += __shfl(hreg[t], i) * crv;
  }
  #pragma unroll
  for (int t=0; t<NB; ++t){
    if (t < cnt){
      float id = invd[nb0+t];
      mreg[t] = lk(aggr[(size_t)(nb0+t)*DD + lane]*id + mac[t] + cb[lane]);
    } else mreg[t] = 0.f;
  }
  float air[NB]={}, aiz[NB]={}, ain[NB]={}, ahr[NB]={}, ahz[NB]={}, ahn[NB]={};
  for (int i=0; i<DD; ++i){
    float w0 = wihT[i*192 + lane], w1 = wihT[i*192 + 64 + lane], w2 = wihT[i*192 + 128 + lane];
    float v0 = whhT[i*192 + lane], v1 = whhT[i*192 + 64 + lane], v2 = whhT[i*192 + 128 + lane];
    #pragma unroll
    for (int t=0; t<NB; ++t){
      float mi = __shfl(mreg[t], i), hi = __shfl(hreg[t], i);
      air[t] += mi*w0; aiz[t] += mi*w1; ain[t] += mi*w2;
      ahr[t] += hi*v0; ahz[t] += hi*v1; ahn[t] += hi*v2;
    }
  }
  float bi0 = bih[lane], bi1 = bih[64+lane], bi2 = bih[128+lane];
  float bh0 = bhh[lane], bh1 = bhh[64+lane], bh2 = bhh[128+lane];
  #pragma unroll
  for (int t=0; t<NB; ++t){
    if (t < cnt){
      float r = sg(air[t]+bi0 + ahr[t]+bh0);
      float z = sg(aiz[t]+bi1 + ahz[t]+bh1);
      float n = tanhf(ain[t]+bi2 + r*(ahn[t]+bh2));
      float nh = (1.f - z)*n + z*hreg[t];
      h[(size_t)(nb0+t)*DD + lane] = nh;
      hbf[(size_t)(nb0+t)*DD + lane] = f2bf(nh);
    }
  }
}

// ---------- heads ----------
__global__ __launch_bounds__(256) void k_jbond(const float* __restrict__ h, const int* __restrict__ idx,
                        const float* __restrict__ w1T, const float* __restrict__ b1,
                        const float* __restrict__ w2, const float* __restrict__ b2,
                        float* __restrict__ jtmp){
  int wid = (blockIdx.x*blockDim.x + threadIdx.x) >> 6;
  int lane = threadIdx.x & 63;
  if (wid >= NJ*2) return;
  int a = idx[wid];
  float f = h[(size_t)a*DD + lane];
  float acc = b1[lane];
  for (int i=0; i<DD; ++i) acc += __shfl(f, i) * w1T[i*DD + lane];
  float p = lk(acc) * w2[lane];
  #pragma unroll
  for (int off=32; off; off>>=1) p += __shfl_xor(p, off);
  if (lane == 0) jtmp[wid] = p + b2[0];
}
__global__ __launch_bounds__(256) void k_jmean(const float* __restrict__ jtmp, float* __restrict__ o){
  int j = blockIdx.x*blockDim.x + threadIdx.x;
  if (j < NJ) o[j] = 0.5f*(jtmp[2*j] + jtmp[2*j+1]);
}
__global__ __launch_bounds__(256) void k_stem1(const float* __restrict__ h, const int* __restrict__ idx,
                        const float* __restrict__ w1T, const float* __restrict__ b1,
                        float* __restrict__ st1){
  int wid = (blockIdx.x*blockDim.x + threadIdx.x) >> 6;
  int lane = threadIdx.x & 63;
  if (wid >= NS) return;
  int a = idx[wid];
  float f = h[(size_t)a*DD + lane];
  float acc = b1[lane];
  for (int i=0; i<DD; ++i) acc += __shfl(f, i) * w1T[i*DD + lane];
  st1[(size_t)wid*DD + lane] = lk(acc);
}
__global__ __launch_bounds__(256) void k_stem2(const float* __restrict__ st1, const float* __restrict__ w2,
                        const float* __restrict__ b2, float* __restrict__ o){
  int i = blockIdx.x*blockDim.x + threadIdx.x;
  if (i >= NS*NO) return;
  int r = i / NO, c = i - r*NO;
  float acc = b2[c];
  const float* t1 = st1 + (size_t)r*DD;
  const float* wr = w2 + (size_t)c*DD;
  for (int k=0; k<DD; ++k) acc += t1[k]*wr[k];
  o[i] = acc;
}

// ---------- Set2Set (1 step, zero init state) ----------
__global__ void k_qvec(const float* __restrict__ bih, const float* __restrict__ bhh, float* __restrict__ qv){
  int g = threadIdx.x;
  float gi = bih[g] + bhh[g];
  float gg = bih[128+g] + bhh[128+g];
  float go = bih[192+g] + bhh[192+g];
  float c = sg(gi)*tanhf(gg);
  qv[g] = sg(go)*tanhf(c);
}
__global__ __launch_bounds__(256) void k_e(const float* __restrict__ h, const float* __restrict__ qv,
                    const int* __restrict__ batch, float* __restrict__ evec, unsigned* __restrict__ emax){
  int n = (blockIdx.x*blockDim.x + threadIdx.x) >> 6;
  int lane = threadIdx.x & 63;
  if (n >= NN) return;
  float p = h[(size_t)n*DD + lane] * qv[lane];
  #pragma unroll
  for (int off=32; off; off>>=1) p += __shfl_xor(p, off);
  if (lane == 0){
    evec[n] = p;
    atomicMax(&emax[batch[n]], fenc(p));
  }
}
__global__ __launch_bounds__(256) void k_exden(float* __restrict__ evec, const unsigned* __restrict__ emax,
                        const int* __restrict__ batch, float* __restrict__ denom){
  int n = blockIdx.x*blockDim.x + threadIdx.x;
  if (n >= NN) return;
  float m = fdec(emax[batch[n]]);
  float ex = expf(evec[n] - m);
  evec[n] = ex;
  atomicAdd(&denom[batch[n]], ex);
}
__global__ __launch_bounds__(256) void k_rvec(const float* __restrict__ h, const float* __restrict__ evec,
                       const float* __restrict__ denom, const int* __restrict__ batch,
                       float* __restrict__ rvec){
  int n = (blockIdx.x*blockDim.x + threadIdx.x) >> 6;
  int lane = threadIdx.x & 63;
  if (n >= NN) return;
  int b = batch[n];
  float a = evec[n] / denom[b];
  atomicAdd(&rvec[(size_t)b*DD + lane], a * h[(size_t)n*DD + lane]);
}
__global__ __launch_bounds__(256) void k_gout(const float* __restrict__ qv, const float* __restrict__ rvec,
                       const float* __restrict__ lw, const float* __restrict__ lb, float* __restrict__ o){
  int t = blockIdx.x*blockDim.x + threadIdx.x;
  if (t >= NGG*2) return;
  int g = t >> 1, c = t & 1;
  float acc = lb[c];
  for (int j=0; j<DD; ++j) acc += qv[j]*lw[c*128 + j];
  for (int j=0; j<DD; ++j) acc += rvec[(size_t)g*DD + j]*lw[c*128 + 64 + j];
  o[g*2 + c] = acc;
}

// ---------- host ----------
extern "C" void kernel_launch(void* const* d_in, const int* in_sizes, int n_in,
                              void* d_out_, int out_size, void* d_ws, size_t ws_size,
                              hipStream_t stream){
  const float* x        = (const float*)d_in[0];
  const int*   ei       = (const int*)d_in[1];
  const float* eattr    = (const float*)d_in[2];
  const int*   jbidx    = (const int*)d_in[3];
  const int*   stidx    = (const int*)d_in[4];
  const int*   batch    = (const int*)d_in[5];
  const float* lin0_w   = (const float*)d_in[6];
  const float* lin0_b   = (const float*)d_in[7];
  const float* net1_w   = (const float*)d_in[8];
  const float* net1_b   = (const float*)d_in[9];
  const float* net2_w   = (const float*)d_in[10];
  const float* net2_b   = (const float*)d_in[11];
  const float* conv_root= (const float*)d_in[12];
  const float* conv_b   = (const float*)d_in[13];
  const float* gru_wih  = (const float*)d_in[14];
  const float* gru_whh  = (const float*)d_in[15];
  const float* gru_bih  = (const float*)d_in[16];
  const float* gru_bhh  = (const float*)d_in[17];
  const float* n2s_w1   = (const float*)d_in[18];
  const float* n2s_b1   = (const float*)d_in[19];
  const float* n2s_w2   = (const float*)d_in[20];
  const float* n2s_b2   = (const float*)d_in[21];
  const float* n2j_w1   = (const float*)d_in[22];
  const float* n2j_b1   = (const float*)d_in[23];
  const float* n2j_w2   = (const float*)d_in[24];
  const float* n2j_b2   = (const float*)d_in[25];
  const float* lstm_bih = (const float*)d_in[28];
  const float* lstm_bhh = (const float*)d_in[29];
  const float* lout_w   = (const float*)d_in[30];
  const float* lout_b   = (const float*)d_in[31];
  float* out = (float*)d_out_;

  const int* src = ei;
  const int* dst = ei + NE;

  char* ws = (char*)d_ws;
  size_t off = 0;
  auto alloc = [&](size_t bytes)->void*{
    void* p = ws + off; off = (off + bytes + 255) & ~(size_t)255; return p;
  };
  float* h    = (float*)alloc((size_t)NN*DD*4);
  float* aggr = (float*)alloc((size_t)NN*DD*4);
  unsigned short* hbf = (unsigned short*)alloc((size_t)NPAD*DD*2);
  unsigned short* e1s = (unsigned short*)alloc((size_t)NE*DD*2);
  unsigned short* w2x = (unsigned short*)alloc((size_t)CTOT*DD*2);
  int* degS   = (int*)alloc((size_t)NPAD*4);
  int* cnt    = (int*)alloc((size_t)NPAD*4);
  int* rowptr = (int*)alloc((size_t)(NPAD+1)*4);
  int* sSrc   = (int*)alloc((size_t)NE*4);
  int* sDst   = (int*)alloc((size_t)NE*4);
  int* sEid   = (int*)alloc((size_t)NE*4);
  float* wihT = (float*)alloc((size_t)DD*192*4);
  float* whhT = (float*)alloc((size_t)DD*192*4);
  float* w1jT = (float*)alloc((size_t)DD*DD*4);
  float* w1sT = (float*)alloc((size_t)DD*DD*4);
  float* invd = (float*)alloc((size_t)NN*4);
  float* evec = (float*)alloc((size_t)NN*4);
  unsigned* emax = (unsigned*)alloc((size_t)NGG*4);
  float* denom = (float*)alloc((size_t)NGG*4);
  float* rvec  = (float*)alloc((size_t)NGG*DD*4);
  float* qv    = (float*)alloc((size_t)DD*4);
  float* jtmp  = (float*)alloc((size_t)NJ*2*4);
  float* st1   = (float*)alloc((size_t)NS*DD*4);

  const int LDSB = 16*ASTRIDE;   // 133632
  static bool attr_set = false;  // idempotent host-side attribute (not stream state)
  hipFuncSetAttribute((const void*)k_fused8, hipFuncAttributeMaxDynamicSharedMemorySize, LDSB);

  // ---- setup ----
  hipMemsetAsync(invd, 0, (size_t)NN*4, stream);
  hipMemsetAsync(degS, 0, (size_t)NPAD*4, stream);
  hipMemsetAsync(cnt,  0, (size_t)NPAD*4, stream);
  hipMemsetAsync(hbf,  0, (size_t)NPAD*DD*2, stream);   // zero pad rows 25000..25007
  k_lin0<<<6250, 256, 0, stream>>>(x, lin0_w, lin0_b, h, hbf);
  k_w2x<<<1040, 256, 0, stream>>>(net2_w, net2_b, w2x);
  k_tr<<<48, 256, 0, stream>>>(gru_wih, wihT, 192, 64);
  k_tr<<<48, 256, 0, stream>>>(gru_whh, whhT, 192, 64);
  k_tr<<<16, 256, 0, stream>>>(n2j_w1, w1jT, 64, 64);
  k_tr<<<16, 256, 0, stream>>>(n2s_w1, w1sT, 64, 64);
  k_deg<<<391, 256, 0, stream>>>(dst, invd);
  k_invd<<<98, 256, 0, stream>>>(invd);
  // edge sort by src
  k_hist<<<391, 256, 0, stream>>>(src, degS);
  k_scan<<<1, 1024, 0, stream>>>(degS, rowptr);
  k_scatter<<<391, 256, 0, stream>>>(src, dst, rowptr, cnt, sSrc, sDst, sEid);
  k_e1s<<<25000, 256, 0, stream>>>(eattr, net1_w, net1_b, sEid, e1s);

  // ---- 6 message-passing + GRU iterations ----
  for (int it=0; it<6; ++it){
    hipMemsetAsync(aggr, 0, (size_t)NN*DD*4, stream);
    k_fused8<<<NBLK, 512, LDSB, stream>>>(w2x, hbf, e1s, sSrc, sDst, rowptr, aggr);
    k_gru<<<782, 256, 0, stream>>>(h, hbf, aggr, invd, conv_root, conv_b, wihT, whhT, gru_bih, gru_bhh);
  }

  // ---- heads ----
  k_jbond<<<512, 256, 0, stream>>>(h, jbidx, w1jT, n2j_b1, n2j_w2, n2j_b2, jtmp);
  k_jmean<<<4, 256, 0, stream>>>(jtmp, out + NGG*2 + NS*NO);
  k_stem1<<<512, 256, 0, stream>>>(h, stidx, w1sT, n2s_b1, st1);
  k_stem2<<<840, 256, 0, stream>>>(st1, n2s_w2, n2s_b2, out + NGG*2);

  // ---- Set2Set ----
  hipMemsetAsync(emax, 0, (size_t)NGG*4, stream);
  hipMemsetAsync(denom, 0, (size_t)NGG*4, stream);
  hipMemsetAsync(rvec, 0, (size_t)NGG*DD*4, stream);
  k_qvec<<<1, 64, 0, stream>>>(lstm_bih, lstm_bhh, qv);
  k_e<<<6250, 256, 0, stream>>>(h, qv, batch, evec, emax);
  k_exden<<<98, 256, 0, stream>>>(evec, emax, batch, denom);
  k_rvec<<<6250, 256, 0, stream>>>(h, evec, denom, batch, rvec);
  k_gout<<<4, 256, 0, stream>>>(qv, rvec, lout_w, lout_b, out);
}

// Round 4
// 1583.672 us; speedup vs baseline: 1.0619x; 1.0619x over previous
//
#include <hip/hip_runtime.h>
#include <stdint.h>
#include <stddef.h>

#define NN 25000     // nodes
#define NPAD 25008   // 1563*16
#define NBLK 1563    // node blocks of 16
#define NE 100000    // edges
#define FEAT 16
#define DD 64
#define NGG 512
#define NJ 1024
#define NS 2048
#define NO 105
#define SLOPE 0.01f
#define CTOT 4160    // 4096 A-columns + 64 bias columns
#define ASTRIDE 8352 // bytes per node row in LDS: 4160*2 + 32 pad (16B aligned)

typedef short bf8 __attribute__((ext_vector_type(8)));   // 8 bf16 raw bits (4 VGPR)
typedef float f32x4 __attribute__((ext_vector_type(4)));

__device__ __forceinline__ float lk(float v){ return v > 0.f ? v : SLOPE*v; }
__device__ __forceinline__ unsigned short f2bf(float f){
  unsigned int x = __float_as_uint(f);
  x += 0x7fffu + ((x>>16)&1u);           // round-to-nearest-even
  return (unsigned short)(x>>16);
}
__device__ __forceinline__ float bf2f(unsigned short u){ return __uint_as_float(((unsigned int)u)<<16); }
__device__ __forceinline__ float sg(float x){ return 1.f/(1.f+expf(-x)); }
__device__ __forceinline__ unsigned fenc(float f){ unsigned u = __float_as_uint(f); return (u & 0x80000000u) ? ~u : (u | 0x80000000u); }
__device__ __forceinline__ float fdec(unsigned k){ unsigned u = (k & 0x80000000u) ? (k ^ 0x80000000u) : ~k; return __uint_as_float(u); }

// ---------- setup kernels ----------

// out = leaky(x @ lin0_w.T + lin0_b); also writes bf16 copy; zero-fills hbf pad rows
__global__ __launch_bounds__(256) void k_lin0(const float* __restrict__ x, const float* __restrict__ w,
                       const float* __restrict__ b, float* __restrict__ h, unsigned short* __restrict__ hbf){
  int wid = (blockIdx.x*blockDim.x + threadIdx.x) >> 6;
  int lane = threadIdx.x & 63;
  if (wid >= NPAD) return;
  if (wid >= NN){ hbf[(size_t)wid*DD + lane] = 0; return; }
  float xv = lane < FEAT ? x[wid*FEAT + lane] : 0.f;
  float acc = b[lane];
  #pragma unroll
  for (int f=0; f<FEAT; ++f) acc += __shfl(xv, f) * w[lane*FEAT + f];
  float v = lk(acc);
  h[wid*DD + lane] = v;
  hbf[(size_t)wid*DD + lane] = f2bf(v);
}

// w2x[c*64+i]: c<4096 -> bf16(net2_w[i*4096+c]) ; c=4096+o -> bf16(net2_b[i*64+o])
__global__ __launch_bounds__(256) void k_w2x(const float* __restrict__ w2, const float* __restrict__ b2,
                                             unsigned short* __restrict__ o){
  int t = blockIdx.x*blockDim.x + threadIdx.x;
  if (t >= CTOT*DD) return;
  int c = t >> 6, i = t & 63;
  float v = (c < 4096) ? w2[(size_t)i*4096 + c] : b2[i*64 + (c - 4096)];
  o[t] = f2bf(v);
}

// generic transpose: T[c*R + r] = M[r*C + c]
__global__ __launch_bounds__(256) void k_tr(const float* __restrict__ m, float* __restrict__ t, int R, int C){
  int i = blockIdx.x*blockDim.x + threadIdx.x;
  if (i >= R*C) return;
  int r = i / C, c = i - r*C;
  t[c*R + r] = m[i];
}

__global__ __launch_bounds__(256) void k_deg(const int* __restrict__ dst, float* __restrict__ deg){
  int e = blockIdx.x*blockDim.x + threadIdx.x;
  if (e < NE) atomicAdd(&deg[dst[e]], 1.f);
}
__global__ __launch_bounds__(256) void k_invd(float* __restrict__ d){
  int n = blockIdx.x*blockDim.x + threadIdx.x;
  if (n < NN) d[n] = d[n] > 0.f ? 1.f/d[n] : 0.f;
}

// ---------- edge sort by src (counting sort) ----------
__global__ __launch_bounds__(256) void k_hist(const int* __restrict__ src, int* __restrict__ degS){
  int e = blockIdx.x*blockDim.x + threadIdx.x;
  if (e < NE) atomicAdd(&degS[src[e]], 1);
}
// single-block scan via wave shuffles: rowptr[0..NPAD]
__global__ __launch_bounds__(1024) void k_scan(const int* __restrict__ degS, int* __restrict__ rowptr){
  __shared__ int wsum[16];
  __shared__ int base;
  int tid = threadIdx.x, lane = tid & 63, wv = tid >> 6;
  if (tid == 0){ base = 0; rowptr[0] = 0; }
  __syncthreads();
  for (int c0 = 0; c0 < NPAD; c0 += 1024){
    int i = c0 + tid;
    int v = (i < NPAD) ? degS[i] : 0;
    int s = v;
    #pragma unroll
    for (int off=1; off<64; off<<=1){
      int t = __shfl_up(s, off);
      if (lane >= off) s += t;
    }
    if (lane == 63) wsum[wv] = s;
    __syncthreads();
    if (wv == 0 && lane < 16){
      int ws = wsum[lane];
      #pragma unroll
      for (int off=1; off<16; off<<=1){
        int t = __shfl_up(ws, off);
        if (lane >= off) ws += t;
      }
      wsum[lane] = ws;
    }
    __syncthreads();
    int wbase = (wv == 0) ? 0 : wsum[wv-1];
    if (i < NPAD) rowptr[i+1] = base + wbase + s;
    __syncthreads();
    if (tid == 0) base += wsum[15];
    __syncthreads();
  }
}
__global__ __launch_bounds__(256) void k_scatter(const int* __restrict__ src, const int* __restrict__ dst,
                         const int* __restrict__ rowptr, int* __restrict__ cnt,
                         int* __restrict__ sSrc, int* __restrict__ sDst, int* __restrict__ sEid){
  int e = blockIdx.x*blockDim.x + threadIdx.x;
  if (e >= NE) return;
  int s = src[e];
  int pos = rowptr[s] + atomicAdd(&cnt[s], 1);
  sSrc[pos] = s; sDst[pos] = dst[e]; sEid[pos] = e;
}
// e1 sorted: e1s[pos][k] = bf16(leaky(edge_attr[sEid[pos]] @ net1_w.T + net1_b))
__global__ __launch_bounds__(256) void k_e1s(const float* __restrict__ ea, const float* __restrict__ w,
                     const float* __restrict__ b, const int* __restrict__ sEid,
                     unsigned short* __restrict__ e1s){
  int t = blockIdx.x*blockDim.x + threadIdx.x;   // t = pos*64 + k
  if (t >= NE*DD) return;
  int pos = t >> 6, k = t & 63;
  int e = sEid[pos];
  float acc = b[k];
  #pragma unroll
  for (int a=0; a<4; ++a) acc += ea[e*4+a] * w[k*4+a];
  e1s[t] = f2bf(lk(acc));
}

// ---------- fused: per 16-node block, A-tile in LDS, then edge matvecs ----------
// 16 waves (1024 threads). Phase A: A[c][n] = sum_i w2x[c][i]*hbf[n][i] (MFMA), bf16 into LDS.
// Phase B: per sorted edge of block's nodes: msg[o] = sum_k e1[k]*A[n][o*64+k] + A[n][4096+o]
__global__ __launch_bounds__(1024) void k_fused8(const unsigned short* __restrict__ w2x,
                                                const unsigned short* __restrict__ hbf,
                                                const unsigned short* __restrict__ e1s,
                                                const int* __restrict__ sSrc, const int* __restrict__ sDst,
                                                const int* __restrict__ rowptr,
                                                float* __restrict__ aggr){
  extern __shared__ char smem[];
  int lane = threadIdx.x & 63;
  int wv   = threadIdx.x >> 6;           // 0..15
  int n0   = blockIdx.x * 16;
  int r16 = lane & 15, kg = lane >> 4;

  // persistent B-fragments: bf16 h rows of the 16 nodes
  const unsigned short* hp = hbf + (size_t)(n0 + r16)*DD;
  bf8 bh0 = *(const bf8*)(hp + kg*8);
  bf8 bh1 = *(const bf8*)(hp + 32 + kg*8);

  // phase A: 260 c-tiles round-robin over 16 waves
  for (int t = wv; t < 260; t += 16){
    const unsigned short* wp = w2x + (size_t)t*1024 + r16*64;
    bf8 a0 = *(const bf8*)(wp + kg*8);
    bf8 a1 = *(const bf8*)(wp + 32 + kg*8);
    f32x4 acc = {0.f,0.f,0.f,0.f};
    acc = __builtin_amdgcn_mfma_f32_16x16x32_bf16(a0, bh0, acc, 0,0,0);
    acc = __builtin_amdgcn_mfma_f32_16x16x32_bf16(a1, bh1, acc, 0,0,0);
    unsigned u0 = (unsigned)f2bf(acc[0]) | ((unsigned)f2bf(acc[1]) << 16);
    unsigned u1 = (unsigned)f2bf(acc[2]) | ((unsigned)f2bf(acc[3]) << 16);
    unsigned long long ull = (unsigned long long)u0 | ((unsigned long long)u1 << 32);
    *(unsigned long long*)(smem + (size_t)r16*ASTRIDE + t*32 + kg*8) = ull;
  }
  __syncthreads();

  // phase B: edges of these 16 nodes
  int estart = rowptr[n0], eend = rowptr[n0 + 16];
  int rg = lane >> 3, cg = lane & 7;
  for (int ei = estart + wv; ei < eend; ei += 16){
    int nl = sSrc[ei] - n0;
    int d  = sDst[ei];
    bf8 ef = *(const bf8*)(e1s + (size_t)ei*DD + cg*8);
    float e1f[8];
    #pragma unroll
    for (int j=0; j<8; ++j) e1f[j] = bf2f((unsigned short)ef[j]);
    const char* ab = smem + (size_t)nl*ASTRIDE;
    float acc8[8];
    #pragma unroll
    for (int st=0; st<8; ++st){
      bf8 Av = *(const bf8*)(ab + (st*8 + rg)*128 + cg*16);
      float s = 0.f;
      #pragma unroll
      for (int j=0; j<8; ++j) s += bf2f((unsigned short)Av[j]) * e1f[j];
      acc8[st] = s;
    }
    #pragma unroll
    for (int off=1; off<8; off<<=1)
      #pragma unroll
      for (int st=0; st<8; ++st) acc8[st] += __shfl_xor(acc8[st], off);
    int o = cg*8 + rg;
    float v = acc8[0];
    #pragma unroll
    for (int j=1; j<8; ++j) v = (cg == j) ? acc8[j] : v;
    v += bf2f(*(const unsigned short*)(ab + 8192 + o*2));
    atomicAdd(&aggr[(size_t)d*DD + o], v);
  }
}

// ---------- fused NNConv-root + GRU (also emits bf16 h; zeroes aggr for next iter) ----------
#define NB 8
__global__ __launch_bounds__(256) void k_gru(float* __restrict__ h, unsigned short* __restrict__ hbf,
                      float* __restrict__ aggr,
                      const float* __restrict__ invd,
                      const float* __restrict__ cr, const float* __restrict__ cb,
                      const float* __restrict__ wihT, const float* __restrict__ whhT,
                      const float* __restrict__ bih, const float* __restrict__ bhh){
  int wid = (blockIdx.x*blockDim.x + threadIdx.x) >> 6;
  int lane = threadIdx.x & 63;
  int nb0 = wid * NB;
  if (nb0 >= NN) return;
  int cnt = NN - nb0 < NB ? NN - nb0 : NB;

  float hreg[NB], mreg[NB], mac[NB];
  #pragma unroll
  for (int t=0; t<NB; ++t){ hreg[t] = (t<cnt) ? h[(size_t)(nb0+t)*DD + lane] : 0.f; mac[t]=0.f; }
  for (int i=0; i<DD; ++i){
    float crv = cr[i*DD + lane];
    #pragma unroll
    for (int t=0; t<NB; ++t) mac[t] += __shfl(hreg[t], i) * crv;
  }
  #pragma unroll
  for (int t=0; t<NB; ++t){
    if (t < cnt){
      float id = invd[nb0+t];
      mreg[t] = lk(aggr[(size_t)(nb0+t)*DD + lane]*id + mac[t] + cb[lane]);
      aggr[(size_t)(nb0+t)*DD + lane] = 0.f;    // pre-zero for next iteration's scatter
    } else mreg[t] = 0.f;
  }
  float air[NB]={}, aiz[NB]={}, ain[NB]={}, ahr[NB]={}, ahz[NB]={}, ahn[NB]={};
  for (int i=0; i<DD; ++i){
    float w0 = wihT[i*192 + lane], w1 = wihT[i*192 + 64 + lane], w2 = wihT[i*192 + 128 + lane];
    float v0 = whhT[i*192 + lane], v1 = whhT[i*192 + 64 + lane], v2 = whhT[i*192 + 128 + lane];
    #pragma unroll
    for (int t=0; t<NB; ++t){
      float mi = __shfl(mreg[t], i), hi = __shfl(hreg[t], i);
      air[t] += mi*w0; aiz[t] += mi*w1; ain[t] += mi*w2;
      ahr[t] += hi*v0; ahz[t] += hi*v1; ahn[t] += hi*v2;
    }
  }
  float bi0 = bih[lane], bi1 = bih[64+lane], bi2 = bih[128+lane];
  float bh0 = bhh[lane], bh1 = bhh[64+lane], bh2 = bhh[128+lane];
  #pragma unroll
  for (int t=0; t<NB; ++t){
    if (t < cnt){
      float r = sg(air[t]+bi0 + ahr[t]+bh0);
      float z = sg(aiz[t]+bi1 + ahz[t]+bh1);
      float n = tanhf(ain[t]+bi2 + r*(ahn[t]+bh2));
      float nh = (1.f - z)*n + z*hreg[t];
      h[(size_t)(nb0+t)*DD + lane] = nh;
      hbf[(size_t)(nb0+t)*DD + lane] = f2bf(nh);
    }
  }
}

// ---------- heads ----------
__global__ __launch_bounds__(256) void k_jbond(const float* __restrict__ h, const int* __restrict__ idx,
                        const float* __restrict__ w1T, const float* __restrict__ b1,
                        const float* __restrict__ w2, const float* __restrict__ b2,
                        float* __restrict__ jtmp){
  int wid = (blockIdx.x*blockDim.x + threadIdx.x) >> 6;
  int lane = threadIdx.x & 63;
  if (wid >= NJ*2) return;
  int a = idx[wid];
  float f = h[(size_t)a*DD + lane];
  float acc = b1[lane];
  for (int i=0; i<DD; ++i) acc += __shfl(f, i) * w1T[i*DD + lane];
  float p = lk(acc) * w2[lane];
  #pragma unroll
  for (int off=32; off; off>>=1) p += __shfl_xor(p, off);
  if (lane == 0) jtmp[wid] = p + b2[0];
}
__global__ __launch_bounds__(256) void k_jmean(const float* __restrict__ jtmp, float* __restrict__ o){
  int j = blockIdx.x*blockDim.x + threadIdx.x;
  if (j < NJ) o[j] = 0.5f*(jtmp[2*j] + jtmp[2*j+1]);
}
__global__ __launch_bounds__(256) void k_stem1(const float* __restrict__ h, const int* __restrict__ idx,
                        const float* __restrict__ w1T, const float* __restrict__ b1,
                        float* __restrict__ st1){
  int wid = (blockIdx.x*blockDim.x + threadIdx.x) >> 6;
  int lane = threadIdx.x & 63;
  if (wid >= NS) return;
  int a = idx[wid];
  float f = h[(size_t)a*DD + lane];
  float acc = b1[lane];
  for (int i=0; i<DD; ++i) acc += __shfl(f, i) * w1T[i*DD + lane];
  st1[(size_t)wid*DD + lane] = lk(acc);
}
// w2T[k*NO + c] layout -> coalesced inner loop
__global__ __launch_bounds__(256) void k_stem2(const float* __restrict__ st1, const float* __restrict__ w2T,
                        const float* __restrict__ b2, float* __restrict__ o){
  int i = blockIdx.x*blockDim.x + threadIdx.x;
  if (i >= NS*NO) return;
  int r = i / NO, c = i - r*NO;
  float acc = b2[c];
  const float* t1 = st1 + (size_t)r*DD;
  for (int k=0; k<DD; ++k) acc += t1[k]*w2T[k*NO + c];
  o[i] = acc;
}

// ---------- Set2Set (1 step, zero init state) ----------
__global__ void k_qvec(const float* __restrict__ bih, const float* __restrict__ bhh, float* __restrict__ qv){
  int g = threadIdx.x;
  float gi = bih[g] + bhh[g];
  float gg = bih[128+g] + bhh[128+g];
  float go = bih[192+g] + bhh[192+g];
  float c = sg(gi)*tanhf(gg);
  qv[g] = sg(go)*tanhf(c);
}
__global__ __launch_bounds__(256) void k_e(const float* __restrict__ h, const float* __restrict__ qv,
                    const int* __restrict__ batch, float* __restrict__ evec, unsigned* __restrict__ emax){
  int n = (blockIdx.x*blockDim.x + threadIdx.x) >> 6;
  int lane = threadIdx.x & 63;
  if (n >= NN) return;
  float p = h[(size_t)n*DD + lane] * qv[lane];
  #pragma unroll
  for (int off=32; off; off>>=1) p += __shfl_xor(p, off);
  if (lane == 0){
    evec[n] = p;
    atomicMax(&emax[batch[n]], fenc(p));
  }
}
__global__ __launch_bounds__(256) void k_exden(float* __restrict__ evec, const unsigned* __restrict__ emax,
                        const int* __restrict__ batch, float* __restrict__ denom){
  int n = blockIdx.x*blockDim.x + threadIdx.x;
  if (n >= NN) return;
  float m = fdec(emax[batch[n]]);
  float ex = expf(evec[n] - m);
  evec[n] = ex;
  atomicAdd(&denom[batch[n]], ex);
}
__global__ __launch_bounds__(256) void k_rvec(const float* __restrict__ h, const float* __restrict__ evec,
                       const float* __restrict__ denom, const int* __restrict__ batch,
                       float* __restrict__ rvec){
  int n = (blockIdx.x*blockDim.x + threadIdx.x) >> 6;
  int lane = threadIdx.x & 63;
  if (n >= NN) return;
  int b = batch[n];
  float a = evec[n] / denom[b];
  atomicAdd(&rvec[(size_t)b*DD + lane], a * h[(size_t)n*DD + lane]);
}
__global__ __launch_bounds__(256) void k_gout(const float* __restrict__ qv, const float* __restrict__ rvec,
                       const float* __restrict__ lw, const float* __restrict__ lb, float* __restrict__ o){
  int t = blockIdx.x*blockDim.x + threadIdx.x;
  if (t >= NGG*2) return;
  int g = t >> 1, c = t & 1;
  float acc = lb[c];
  for (int j=0; j<DD; ++j) acc += qv[j]*lw[c*128 + j];
  for (int j=0; j<DD; ++j) acc += rvec[(size_t)g*DD + j]*lw[c*128 + 64 + j];
  o[g*2 + c] = acc;
}

// ---------- host ----------
extern "C" void kernel_launch(void* const* d_in, const int* in_sizes, int n_in,
                              void* d_out_, int out_size, void* d_ws, size_t ws_size,
                              hipStream_t stream){
  const float* x        = (const float*)d_in[0];
  const int*   ei       = (const int*)d_in[1];
  const float* eattr    = (const float*)d_in[2];
  const int*   jbidx    = (const int*)d_in[3];
  const int*   stidx    = (const int*)d_in[4];
  const int*   batch    = (const int*)d_in[5];
  const float* lin0_w   = (const float*)d_in[6];
  const float* lin0_b   = (const float*)d_in[7];
  const float* net1_w   = (const float*)d_in[8];
  const float* net1_b   = (const float*)d_in[9];
  const float* net2_w   = (const float*)d_in[10];
  const float* net2_b   = (const float*)d_in[11];
  const float* conv_root= (const float*)d_in[12];
  const float* conv_b   = (const float*)d_in[13];
  const float* gru_wih  = (const float*)d_in[14];
  const float* gru_whh  = (const float*)d_in[15];
  const float* gru_bih  = (const float*)d_in[16];
  const float* gru_bhh  = (const float*)d_in[17];
  const float* n2s_w1   = (const float*)d_in[18];
  const float* n2s_b1   = (const float*)d_in[19];
  const float* n2s_w2   = (const float*)d_in[20];
  const float* n2s_b2   = (const float*)d_in[21];
  const float* n2j_w1   = (const float*)d_in[22];
  const float* n2j_b1   = (const float*)d_in[23];
  const float* n2j_w2   = (const float*)d_in[24];
  const float* n2j_b2   = (const float*)d_in[25];
  const float* lstm_bih = (const float*)d_in[28];
  const float* lstm_bhh = (const float*)d_in[29];
  const float* lout_w   = (const float*)d_in[30];
  const float* lout_b   = (const float*)d_in[31];
  float* out = (float*)d_out_;

  const int* src = ei;
  const int* dst = ei + NE;

  char* ws = (char*)d_ws;
  size_t off = 0;
  auto alloc = [&](size_t bytes)->void*{
    void* p = ws + off; off = (off + bytes + 255) & ~(size_t)255; return p;
  };
  float* h    = (float*)alloc((size_t)NN*DD*4);
  float* aggr = (float*)alloc((size_t)NN*DD*4);
  unsigned short* hbf = (unsigned short*)alloc((size_t)NPAD*DD*2);
  unsigned short* e1s = (unsigned short*)alloc((size_t)NE*DD*2);
  unsigned short* w2x = (unsigned short*)alloc((size_t)CTOT*DD*2);
  int* degS   = (int*)alloc((size_t)NPAD*4);          // zeroed (contiguous group start)
  int* cnt    = (int*)alloc((size_t)NPAD*4);          // zeroed
  float* invd = (float*)alloc((size_t)NN*4);          // zeroed (group end)
  int* rowptr = (int*)alloc((size_t)(NPAD+1)*4);
  int* sSrc   = (int*)alloc((size_t)NE*4);
  int* sDst   = (int*)alloc((size_t)NE*4);
  int* sEid   = (int*)alloc((size_t)NE*4);
  float* wihT = (float*)alloc((size_t)DD*192*4);
  float* whhT = (float*)alloc((size_t)DD*192*4);
  float* w1jT = (float*)alloc((size_t)DD*DD*4);
  float* w1sT = (float*)alloc((size_t)DD*DD*4);
  float* w2sT = (float*)alloc((size_t)DD*NO*4);
  float* evec = (float*)alloc((size_t)NN*4);
  unsigned* emax = (unsigned*)alloc((size_t)NGG*4);   // zeroed (contiguous group)
  float* denom = (float*)alloc((size_t)NGG*4);        // zeroed
  float* rvec  = (float*)alloc((size_t)NGG*DD*4);     // zeroed (group end)
  float* qv    = (float*)alloc((size_t)DD*4);
  float* jtmp  = (float*)alloc((size_t)NJ*2*4);
  float* st1   = (float*)alloc((size_t)NS*DD*4);

  const int LDSB = 16*ASTRIDE;   // 133632
  hipFuncSetAttribute((const void*)k_fused8, hipFuncAttributeMaxDynamicSharedMemorySize, LDSB);

  // ---- setup ----
  hipMemsetAsync(degS, 0, (size_t)((char*)invd + NN*4 - (char*)degS), stream);  // degS+cnt+invd
  hipMemsetAsync(aggr, 0, (size_t)NN*DD*4, stream);                             // iter-1 scatter target
  k_lin0<<<(NPAD+3)/4, 256, 0, stream>>>(x, lin0_w, lin0_b, h, hbf);
  k_w2x<<<1040, 256, 0, stream>>>(net2_w, net2_b, w2x);
  k_tr<<<48, 256, 0, stream>>>(gru_wih, wihT, 192, 64);
  k_tr<<<48, 256, 0, stream>>>(gru_whh, whhT, 192, 64);
  k_tr<<<16, 256, 0, stream>>>(n2j_w1, w1jT, 64, 64);
  k_tr<<<16, 256, 0, stream>>>(n2s_w1, w1sT, 64, 64);
  k_tr<<<27, 256, 0, stream>>>(n2s_w2, w2sT, NO, DD);
  k_deg<<<391, 256, 0, stream>>>(dst, invd);
  k_invd<<<98, 256, 0, stream>>>(invd);
  // edge sort by src
  k_hist<<<391, 256, 0, stream>>>(src, degS);
  k_scan<<<1, 1024, 0, stream>>>(degS, rowptr);
  k_scatter<<<391, 256, 0, stream>>>(src, dst, rowptr, cnt, sSrc, sDst, sEid);
  k_e1s<<<25000, 256, 0, stream>>>(eattr, net1_w, net1_b, sEid, e1s);

  // ---- 6 message-passing + GRU iterations ----
  for (int it=0; it<6; ++it){
    k_fused8<<<NBLK, 1024, LDSB, stream>>>(w2x, hbf, e1s, sSrc, sDst, rowptr, aggr);
    k_gru<<<782, 256, 0, stream>>>(h, hbf, aggr, invd, conv_root, conv_b, wihT, whhT, gru_bih, gru_bhh);
  }

  // ---- heads ----
  k_jbond<<<512, 256, 0, stream>>>(h, jbidx, w1jT, n2j_b1, n2j_w2, n2j_b2, jtmp);
  k_jmean<<<4, 256, 0, stream>>>(jtmp, out + NGG*2 + NS*NO);
  k_stem1<<<512, 256, 0, stream>>>(h, stidx, w1sT, n2s_b1, st1);
  k_stem2<<<840, 256, 0, stream>>>(st1, w2sT, n2s_b2, out + NGG*2);

  // ---- Set2Set ----
  hipMemsetAsync(emax, 0, (size_t)((char*)(rvec + NGG*DD) - (char*)emax), stream); // emax+denom+rvec
  k_qvec<<<1, 64, 0, stream>>>(lstm_bih, lstm_bhh, qv);
  k_e<<<6250, 256, 0, stream>>>(h, qv, batch, evec, emax);
  k_exden<<<98, 256, 0, stream>>>(evec, emax, batch, denom);
  k_rvec<<<6250, 256, 0, stream>>>(h, evec, denom, batch, rvec);
  k_gout<<<4, 256, 0, stream>>>(qv, rvec, lout_w, lout_b, out);
}